// Round 14
// baseline (648.890 us; speedup 1.0000x reference)
//
#include <hip/hip_runtime.h>
#include <hip/hip_bf16.h>
#include <math.h>

typedef unsigned short u16;
typedef short bf16x8 __attribute__((ext_vector_type(8)));
typedef float f32x4 __attribute__((ext_vector_type(4)));

#define Bz 64
#define Tt 4096
#define Cin 64
#define K1c 128
#define Hh 96
#define T2 1024
#define G4 384
#define NC 109

#define MFMA16(a, b, c) __builtin_amdgcn_mfma_f32_16x16x32_bf16(a, b, c, 0, 0, 0)

__device__ __forceinline__ float bf2f(u16 v) {
  union { unsigned int u; float f; } x; x.u = ((unsigned int)v) << 16; return x.f;
}
__device__ __forceinline__ u16 f2bf(float f) {
  union { unsigned int u; float f; } x; x.f = f;
  unsigned int u = x.u;
  unsigned int r = u + 0x7fff + ((u >> 16) & 1);
  return (u16)(r >> 16);
}

// Gate scale: z-gate rows carry 2*log2(e), i/f/o rows carry log2(e).
__device__ __forceinline__ float gate_scale(int g) {
  const float L2E = 1.44269504f;
  return (g == 0) ? 2.f * L2E : L2E;
}

// ---------------- K0: weight packing + BN folding ----------------
__global__ void k_prep(const float* __restrict__ w1, const float* __restrict__ cb1,
                       const float* __restrict__ g1, const float* __restrict__ b1,
                       const float* __restrict__ m1, const float* __restrict__ v1,
                       const float* __restrict__ w2, const float* __restrict__ cb2,
                       const float* __restrict__ g2, const float* __restrict__ b2,
                       const float* __restrict__ m2, const float* __restrict__ v2,
                       const float* __restrict__ wr, const float* __restrict__ cbr,
                       const float* __restrict__ gr, const float* __restrict__ br,
                       const float* __restrict__ mr, const float* __restrict__ vr,
                       const float* __restrict__ wx, const float* __restrict__ sbia,
                       const float* __restrict__ wh,
                       u16* __restrict__ w1b, u16* __restrict__ w2b,
                       u16* __restrict__ wrb, u16* __restrict__ wxb,
                       float* __restrict__ bperm, u16* __restrict__ whb,
                       float* __restrict__ al1, float* __restrict__ be1,
                       float* __restrict__ al2, float* __restrict__ be2,
                       float* __restrict__ alr, float* __restrict__ ber)
{
  int tid = blockIdx.x * blockDim.x + threadIdx.x;
  int nth = gridDim.x * blockDim.x;
  for (int idx = tid; idx < 128 * 448; idx += nth) {
    int o = idx / 448, k = idx % 448;
    int kt = k >> 6, c = k & 63;
    w1b[idx] = f2bf(w1[(o * 64 + c) * 7 + kt]);
  }
  for (int idx = tid; idx < 96 * 384; idx += nth) {
    int o = idx / 384, k = idx % 384;
    int kk = k >> 7, c = k & 127;
    w2b[idx] = f2bf(w2[(o * 128 + c) * 3 + kk]);
  }
  for (int idx = tid; idx < 96 * 128; idx += nth) {
    wrb[idx] = f2bf(wr[idx]);
  }
  // wxb[row*96 + k] = bf16(wx[(g*96+ch)*96 + k] * gate_scale(g)), row = ch*4+g
  for (int idx = tid; idx < 384 * 96; idx += nth) {
    int row = idx / 96, k = idx % 96;
    int ch = row >> 2, g = row & 3;
    wxb[idx] = f2bf(wx[((size_t)(g * 96 + ch)) * 96 + k] * gate_scale(g));
  }
  // bperm[ch*4+g] = sbia[g*96+ch] * gate_scale(g)
  for (int c = tid; c < 384; c += nth) {
    int ch = c >> 2, g = c & 3;
    bperm[c] = sbia[g * 96 + ch] * gate_scale(g);
  }
  // whb[row*96 + k] = bf16(wh[(g*96+ch)*96 + k] * gate_scale(g)), row = ch*4+g
  for (int idx = tid; idx < 384 * 96; idx += nth) {
    int row = idx / 96, k = idx % 96;
    int ch = row >> 2, g = row & 3;
    whb[idx] = f2bf(wh[((size_t)(g * 96 + ch)) * 96 + k] * gate_scale(g));
  }
  for (int o = tid; o < 128; o += nth) {
    float a = g1[o] / sqrtf(v1[o] + 1e-5f);
    al1[o] = a; be1[o] = b1[o] + (cb1[o] - m1[o]) * a;
  }
  for (int o = tid; o < 96; o += nth) {
    float a = g2[o] / sqrtf(v2[o] + 1e-5f);
    al2[o] = a; be2[o] = b2[o] + (cb2[o] - m2[o]) * a;
    float ar = gr[o] / sqrtf(vr[o] + 1e-5f);
    alr[o] = ar; ber[o] = br[o] + (cbr[o] - mr[o]) * ar;
  }
}

// ---------------- K1: conv1 MFMA implicit GEMM (unchanged) ----------------
__launch_bounds__(256, 2)
__global__ void k_conv1(const float* __restrict__ x, const u16* __restrict__ w1b,
                        const float* __restrict__ al1, const float* __restrict__ be1,
                        u16* __restrict__ out1)
{
  __shared__ __align__(16) u16 xs[134 * 72];
  int tid = threadIdx.x;
  int b = blockIdx.y;
  int t0 = blockIdx.x * 128;
  const float* xb = x + (size_t)b * Tt * Cin;

  for (int idx = tid; idx < 134 * 16; idx += 256) {
    int row = idx >> 4, c4 = (idx & 15) << 2;
    int gt = t0 - 3 + row;
    float4 v = make_float4(0.f, 0.f, 0.f, 0.f);
    if (gt >= 0 && gt < Tt) v = *(const float4*)(xb + (size_t)gt * 64 + c4);
    ushort4 s;
    s.x = f2bf(v.x); s.y = f2bf(v.y); s.z = f2bf(v.z); s.w = f2bf(v.w);
    *(ushort4*)(xs + row * 72 + c4) = s;
  }
  __syncthreads();

  int l = tid & 63;
  int wid = tid >> 6;
  int wm = wid >> 1, wn = wid & 1;
  int lr = l & 15, g = l >> 4;

  f32x4 acc[4][4];
#pragma unroll
  for (int i = 0; i < 4; i++)
#pragma unroll
    for (int j = 0; j < 4; j++) acc[i][j] = (f32x4){0.f, 0.f, 0.f, 0.f};

  const u16* wbase = w1b + (size_t)(wn * 64 + lr) * 448;

  for (int s = 0; s < 14; ++s) {
    int kt = s >> 1;
    int cofs = ((s & 1) << 5) + (g << 3);
    const u16* xrow = xs + (wm * 64 + lr + kt) * 72 + cofs;
    bf16x8 a0 = *(const bf16x8*)(xrow);
    bf16x8 a1 = *(const bf16x8*)(xrow + 16 * 72);
    bf16x8 a2 = *(const bf16x8*)(xrow + 32 * 72);
    bf16x8 a3 = *(const bf16x8*)(xrow + 48 * 72);
    int ko = (s << 5) + (g << 3);
    bf16x8 b0 = *(const bf16x8*)(wbase + ko);
    bf16x8 b1 = *(const bf16x8*)(wbase + 16 * 448 + ko);
    bf16x8 b2 = *(const bf16x8*)(wbase + 32 * 448 + ko);
    bf16x8 b3 = *(const bf16x8*)(wbase + 48 * 448 + ko);
    acc[0][0] = MFMA16(a0, b0, acc[0][0]);
    acc[0][1] = MFMA16(a0, b1, acc[0][1]);
    acc[0][2] = MFMA16(a0, b2, acc[0][2]);
    acc[0][3] = MFMA16(a0, b3, acc[0][3]);
    acc[1][0] = MFMA16(a1, b0, acc[1][0]);
    acc[1][1] = MFMA16(a1, b1, acc[1][1]);
    acc[1][2] = MFMA16(a1, b2, acc[1][2]);
    acc[1][3] = MFMA16(a1, b3, acc[1][3]);
    acc[2][0] = MFMA16(a2, b0, acc[2][0]);
    acc[2][1] = MFMA16(a2, b1, acc[2][1]);
    acc[2][2] = MFMA16(a2, b2, acc[2][2]);
    acc[2][3] = MFMA16(a2, b3, acc[2][3]);
    acc[3][0] = MFMA16(a3, b0, acc[3][0]);
    acc[3][1] = MFMA16(a3, b1, acc[3][1]);
    acc[3][2] = MFMA16(a3, b2, acc[3][2]);
    acc[3][3] = MFMA16(a3, b3, acc[3][3]);
  }

  int colb = wn * 64 + lr;
  int rowb = t0 + wm * 64 + (l >> 4) * 4;
#pragma unroll
  for (int nf = 0; nf < 4; nf++) {
    int col = colb + nf * 16;
    float A = al1[col], Bt = be1[col];
#pragma unroll
    for (int mf = 0; mf < 4; mf++) {
      int row = rowb + mf * 16;
#pragma unroll
      for (int r = 0; r < 4; r++) {
        float v = acc[mf][nf][r];
        v = fmaxf(v * A + Bt, 0.f);
        out1[((size_t)b * Tt + row + r) * 128 + col] = f2bf(v);
      }
    }
  }
}

// ---------------- K2: conv2 MFMA implicit GEMM + fused residual -> seqb bf16 (unchanged) ----------------
__launch_bounds__(256, 4)
__global__ void k_conv2(const u16* __restrict__ out1, const u16* __restrict__ w2b,
                        const u16* __restrict__ wrb,
                        const float* __restrict__ al2, const float* __restrict__ be2,
                        const float* __restrict__ alr, const float* __restrict__ ber,
                        u16* __restrict__ seqb)
{
  int tid = threadIdx.x;
  int b = blockIdx.y;
  int t20 = blockIdx.x * 64;
  int l = tid & 63;
  int wid = tid >> 6;
  int wm = wid >> 1, wn = wid & 1;    // wave tile 32 x 48
  int lr = l & 15, g = l >> 4;

  f32x4 acc[2][3], accr[2][3];
#pragma unroll
  for (int i = 0; i < 2; i++)
#pragma unroll
    for (int j = 0; j < 3; j++) {
      acc[i][j] = (f32x4){0.f, 0.f, 0.f, 0.f};
      accr[i][j] = (f32x4){0.f, 0.f, 0.f, 0.f};
    }

  const u16* ob = out1 + (size_t)b * Tt * 128;
  int colb = wn * 48 + lr;

#pragma unroll
  for (int f = 0; f < 12; f++) {
    int kk = f >> 2;
    int c = ((f & 3) << 5) + (g << 3);
    bf16x8 a[2];
#pragma unroll
    for (int mf = 0; mf < 2; mf++) {
      int t2 = t20 + wm * 32 + mf * 16 + lr;
      int gt = 4 * t2 + kk - 1;
      if (gt >= 0)
        a[mf] = *(const bf16x8*)(ob + (size_t)gt * 128 + c);
      else
        a[mf] = (bf16x8){0, 0, 0, 0, 0, 0, 0, 0};
    }
#pragma unroll
    for (int nf = 0; nf < 3; nf++) {
      int col = colb + nf * 16;
      bf16x8 bb = *(const bf16x8*)(w2b + (size_t)col * 384 + (f << 5) + (g << 3));
      acc[0][nf] = MFMA16(a[0], bb, acc[0][nf]);
      acc[1][nf] = MFMA16(a[1], bb, acc[1][nf]);
    }
    if (kk == 1) {
#pragma unroll
      for (int nf = 0; nf < 3; nf++) {
        int col = colb + nf * 16;
        bf16x8 br = *(const bf16x8*)(wrb + (size_t)col * 128 + ((f & 3) << 5) + (g << 3));
        accr[0][nf] = MFMA16(a[0], br, accr[0][nf]);
        accr[1][nf] = MFMA16(a[1], br, accr[1][nf]);
      }
    }
  }

  int rowb = t20 + wm * 32 + (l >> 4) * 4;
#pragma unroll
  for (int nf = 0; nf < 3; nf++) {
    int col = colb + nf * 16;
    float A = al2[col], Bt = be2[col];
    float Ar = alr[col], Br = ber[col];
#pragma unroll
    for (int mf = 0; mf < 2; mf++) {
      int row = rowb + mf * 16;
#pragma unroll
      for (int r = 0; r < 4; r++) {
        float v = fmaxf(acc[mf][nf][r] * A + Bt, 0.f) + accr[mf][nf][r] * Ar + Br;
        seqb[((size_t)b * T2 + row + r) * 96 + col] = f2bf(v);
      }
    }
  }
}

// ---------------- K4: sLSTM v11 — time-batched px via MFMA columns ----------------
// 256 threads = 4 waves (1/SIMD), one block per batch (64 blocks).
// px batched over 16 TIMESTEPS using MFMA B-columns (col = timestep):
//   every 16th window, 18 MFMA produce px(t+16..t+31) for this wave's 96 rows
//   into a 32-slot LDS ring (slot = step & 31; writes are >=16 barriers ahead
//   of reads, slots disjoint mod 32). Amortized px cost ~1.2 MFMA/step.
// Recurrence per step: ds_read h (3xb128 broadcast) + own-channel px f32x4 ->
//   18 wh MFMA (C=0) -> cndmask select -> +px -> gate math -> h bf16 write.
// One __syncthreads per step. seq B-frags prefetched 16 windows ahead.
__launch_bounds__(256, 1)
__global__ void k_slstm(const u16* __restrict__ seqb, const u16* __restrict__ whb,
                        const u16* __restrict__ wxb, const float* __restrict__ bperm,
                        float* __restrict__ hsum)
{
  __shared__ __align__(16) float pxring[32][392];
  __shared__ __align__(16) u16 hbufB[2][96];
  int tid = threadIdx.x;
  int b = blockIdx.x;
  int w = tid >> 6;
  int l = tid & 63;
  int grp = l >> 4, lr = l & 15;

  // A-frags: af (wh), wf (wx): row = 96w + 16m + lr, k = kt*32 + grp*8 + reg
  bf16x8 af[6][3], wf[6][3];
#pragma unroll
  for (int m = 0; m < 6; m++) {
    const u16* wrow = whb + (size_t)(96 * w + 16 * m + lr) * 96 + grp * 8;
    const u16* xrow = wxb + (size_t)(96 * w + 16 * m + lr) * 96 + grp * 8;
#pragma unroll
    for (int kt = 0; kt < 3; kt++) {
      af[m][kt] = *(const bf16x8*)(wrow + kt * 32);
      wf[m][kt] = *(const bf16x8*)(xrow + kt * 32);
    }
  }
  f32x4 bias6[6];
#pragma unroll
  for (int m = 0; m < 6; m++)
    bias6[m] = *(const f32x4*)(bperm + 96 * w + 16 * m + 4 * grp);

  bool gl = (lr < 6);
  int ch = 24 * w + 4 * lr + grp;
  const u16* sqB = seqb + (size_t)b * T2 * 96 + grp * 8;

  // prologue: produce px(0..15) into slots 0..15 (B col = timestep lr)
  {
    const u16* sp_ = sqB + (size_t)lr * 96;
    bf16x8 s0 = *(const bf16x8*)(sp_);
    bf16x8 s1 = *(const bf16x8*)(sp_ + 32);
    bf16x8 s2 = *(const bf16x8*)(sp_ + 64);
    f32x4 pc[6];
#pragma unroll
    for (int m = 0; m < 6; m++) {
      pc[m] = MFMA16(wf[m][0], s0, bias6[m]);
      pc[m] = MFMA16(wf[m][1], s1, pc[m]);
      pc[m] = MFMA16(wf[m][2], s2, pc[m]);
    }
#pragma unroll
    for (int m = 0; m < 6; m++)
      *(f32x4*)(&pxring[lr][96 * w + 16 * m + 4 * grp]) = pc[m];
  }
  // prefetch seq B-frags for production at window 0 (steps 16+lr)
  bf16x8 s0, s1, s2;
  {
    int ts = 16 + lr; if (ts > T2 - 1) ts = T2 - 1;
    const u16* sp_ = sqB + (size_t)ts * 96;
    s0 = *(const bf16x8*)(sp_);
    s1 = *(const bf16x8*)(sp_ + 32);
    s2 = *(const bf16x8*)(sp_ + 64);
  }
  if (tid < 96) hbufB[0][tid] = 0;
  float cS = 0.f, nS = 0.f, mS = 0.f, hs = 0.f;
  const f32x4 zero4 = {0.f, 0.f, 0.f, 0.f};
  __syncthreads();

  int p = 0;
  for (int t = 0; t < T2; t++) {
    const u16* hb = hbufB[p] + grp * 8;
    bf16x8 h0 = *(const bf16x8*)(hb);
    bf16x8 h1 = *(const bf16x8*)(hb + 32);
    bf16x8 h2 = *(const bf16x8*)(hb + 64);
    f32x4 pxv = zero4;
    if (gl) pxv = *(const f32x4*)(&pxring[t & 31][96 * w + 16 * lr + 4 * grp]);

    f32x4 acc[6];
#pragma unroll
    for (int m = 0; m < 6; m++) {
      acc[m] = MFMA16(af[m][0], h0, zero4);
      acc[m] = MFMA16(af[m][1], h1, acc[m]);
      acc[m] = MFMA16(af[m][2], h2, acc[m]);
    }

    bool prod = ((t & 15) == 0) && (t + 16 < T2);
    f32x4 pacc[6];
    if (prod) {
#pragma unroll
      for (int m = 0; m < 6; m++) {
        pacc[m] = MFMA16(wf[m][0], s0, bias6[m]);
        pacc[m] = MFMA16(wf[m][1], s1, pacc[m]);
        pacc[m] = MFMA16(wf[m][2], s2, pacc[m]);
      }
    }

    f32x4 x01 = (lr & 1) ? acc[1] : acc[0];
    f32x4 x23 = (lr & 1) ? acc[3] : acc[2];
    f32x4 x45 = (lr & 1) ? acc[5] : acc[4];
    f32x4 y0 = (lr & 2) ? x23 : x01;
    f32x4 pa = (lr & 4) ? x45 : y0;

    if (gl) {
      pa += pxv;
      float zp = pa[0], ip = pa[1], fp = pa[2], op = pa[3];
      float zc = fminf(fmaxf(zp, -86.f), 86.f);
      float ez = exp2f(zc);
      float z = 1.f - 2.f * __builtin_amdgcn_rcpf(ez + 1.f);
      float oc = fminf(fmaxf(op, -60.f), 60.f);
      float o = __builtin_amdgcn_rcpf(1.f + exp2f(-oc));
      float mn = fmaxf(fp + mS, ip);
      float iv = exp2f(ip - mn);
      float fv = exp2f(fp + mS - mn);
      cS = fv * cS + iv * z;
      nS = fv * nS + iv;
      mS = mn;
      float h = o * cS * __builtin_amdgcn_rcpf(fmaxf(nS, 1.f));
      hs += h;
      hbufB[p ^ 1][ch] = f2bf(h);
    }

    if (prod) {
#pragma unroll
      for (int m = 0; m < 6; m++)
        *(f32x4*)(&pxring[(t + 16 + lr) & 31][96 * w + 16 * m + 4 * grp]) = pacc[m];
      int ts = t + 32 + lr; if (ts > T2 - 1) ts = T2 - 1;
      const u16* sp_ = sqB + (size_t)ts * 96;
      s0 = *(const bf16x8*)(sp_);
      s1 = *(const bf16x8*)(sp_ + 32);
      s2 = *(const bf16x8*)(sp_ + 64);
    }
    __syncthreads();
    p ^= 1;
  }
  if (gl) hsum[b * 96 + ch] = hs * (1.f / 1024.f);
}

// ---------------- K5: head (unchanged) ----------------
__launch_bounds__(128)
__global__ void k_head(const float* __restrict__ hsum, const float* __restrict__ fc1w,
                       const float* __restrict__ fc1b, const float* __restrict__ fc2w,
                       const float* __restrict__ fc2b, float* __restrict__ out)
{
  __shared__ float p[96];
  __shared__ float z1[128];
  int tid = threadIdx.x, b = blockIdx.x;
  if (tid < 96) p[tid] = hsum[b * 96 + tid];
  __syncthreads();
  {
    float a = fc1b[tid];
    const float* wr = fc1w + tid * 96;
    for (int h = 0; h < 96; h++) a += p[h] * wr[h];
    z1[tid] = fmaxf(a, 0.f);
  }
  __syncthreads();
  if (tid < NC) {
    float a = fc2b[tid];
    const float* wr = fc2w + tid * 128;
    for (int j = 0; j < 128; j++) a += z1[j] * wr[j];
    out[b * NC + tid] = a;
  }
}

extern "C" void kernel_launch(void* const* d_in, const int* in_sizes, int n_in,
                              void* d_out, int out_size, void* d_ws, size_t ws_size,
                              hipStream_t stream)
{
  const float* x    = (const float*)d_in[0];
  const float* w1   = (const float*)d_in[1];
  const float* cb1  = (const float*)d_in[2];
  const float* g1   = (const float*)d_in[3];
  const float* b1   = (const float*)d_in[4];
  const float* m1   = (const float*)d_in[5];
  const float* v1   = (const float*)d_in[6];
  const float* w2   = (const float*)d_in[7];
  const float* cb2  = (const float*)d_in[8];
  const float* g2   = (const float*)d_in[9];
  const float* b2   = (const float*)d_in[10];
  const float* m2   = (const float*)d_in[11];
  const float* v2   = (const float*)d_in[12];
  const float* wr   = (const float*)d_in[13];
  const float* cbr  = (const float*)d_in[14];
  const float* gr   = (const float*)d_in[15];
  const float* br   = (const float*)d_in[16];
  const float* mr   = (const float*)d_in[17];
  const float* vr   = (const float*)d_in[18];
  const float* wx   = (const float*)d_in[19];
  const float* wh   = (const float*)d_in[20];
  const float* sbia = (const float*)d_in[21];
  const float* fc1w = (const float*)d_in[22];
  const float* fc1b = (const float*)d_in[23];
  const float* fc2w = (const float*)d_in[24];
  const float* fc2b = (const float*)d_in[25];

  char* ws = (char*)d_ws;
  size_t off = 0;
  auto alloc = [&](size_t bytes) -> void* {
    void* p = (void*)(ws + off);
    off = (off + bytes + 255) & ~((size_t)255);
    return p;
  };
  u16*   out1 = (u16*)  alloc((size_t)Bz * Tt * K1c * 2);   // 67.1 MB
  u16*   seqb = (u16*)  alloc((size_t)Bz * T2 * Hh * 2);    // 12.6 MB
  u16*   w1b  = (u16*)  alloc(448 * 128 * 2);
  u16*   w2b  = (u16*)  alloc(96 * 384 * 2);
  u16*   wrb  = (u16*)  alloc(96 * 128 * 2);
  u16*   wxb  = (u16*)  alloc(384 * 96 * 2);
  float* bperm= (float*)alloc(384 * 4);
  u16*   whb  = (u16*)  alloc(384 * 96 * 2);
  float* al1  = (float*)alloc(128 * 4);
  float* be1  = (float*)alloc(128 * 4);
  float* al2  = (float*)alloc(96 * 4);
  float* be2  = (float*)alloc(96 * 4);
  float* alr  = (float*)alloc(96 * 4);
  float* ber  = (float*)alloc(96 * 4);
  float* hsum = (float*)alloc((size_t)Bz * Hh * 4);
  (void)ws_size; (void)in_sizes; (void)n_in; (void)out_size;

  k_prep<<<dim3(224), dim3(256), 0, stream>>>(
      w1, cb1, g1, b1, m1, v1, w2, cb2, g2, b2, m2, v2,
      wr, cbr, gr, br, mr, vr, wx, sbia, wh,
      w1b, w2b, wrb, wxb, bperm, whb, al1, be1, al2, be2, alr, ber);

  k_conv1<<<dim3(Tt / 128, Bz), dim3(256), 0, stream>>>(x, w1b, al1, be1, out1);

  k_conv2<<<dim3(T2 / 64, Bz), dim3(256), 0, stream>>>(out1, w2b, wrb, al2, be2, alr, ber, seqb);

  k_slstm<<<dim3(Bz), dim3(256), 0, stream>>>(seqb, whb, wxb, bperm, hsum);

  k_head<<<dim3(Bz), dim3(128), 0, stream>>>(hsum, fc1w, fc1b, fc2w, fc2b, (float*)d_out);
}

// Round 15
// 566.009 us; speedup vs baseline: 1.1464x; 1.1464x over previous
//
#include <hip/hip_runtime.h>
#include <hip/hip_bf16.h>
#include <math.h>

typedef unsigned short u16;
typedef short bf16x8 __attribute__((ext_vector_type(8)));
typedef float f32x4 __attribute__((ext_vector_type(4)));

#define Bz 64
#define Tt 4096
#define Cin 64
#define K1c 128
#define Hh 96
#define T2 1024
#define G4 384
#define NC 109

#define MFMA16(a, b, c) __builtin_amdgcn_mfma_f32_16x16x32_bf16(a, b, c, 0, 0, 0)

__device__ __forceinline__ float bf2f(u16 v) {
  union { unsigned int u; float f; } x; x.u = ((unsigned int)v) << 16; return x.f;
}
__device__ __forceinline__ u16 f2bf(float f) {
  union { unsigned int u; float f; } x; x.f = f;
  unsigned int u = x.u;
  unsigned int r = u + 0x7fff + ((u >> 16) & 1);
  return (u16)(r >> 16);
}

// Gate scale: z-gate rows carry 2*log2(e), i/f/o rows carry log2(e).
__device__ __forceinline__ float gate_scale(int g) {
  const float L2E = 1.44269504f;
  return (g == 0) ? 2.f * L2E : L2E;
}

// ---------------- K0: weight packing + BN folding ----------------
__global__ void k_prep(const float* __restrict__ w1, const float* __restrict__ cb1,
                       const float* __restrict__ g1, const float* __restrict__ b1,
                       const float* __restrict__ m1, const float* __restrict__ v1,
                       const float* __restrict__ w2, const float* __restrict__ cb2,
                       const float* __restrict__ g2, const float* __restrict__ b2,
                       const float* __restrict__ m2, const float* __restrict__ v2,
                       const float* __restrict__ wr, const float* __restrict__ cbr,
                       const float* __restrict__ gr, const float* __restrict__ br,
                       const float* __restrict__ mr, const float* __restrict__ vr,
                       const float* __restrict__ wx, const float* __restrict__ sbia,
                       const float* __restrict__ wh,
                       u16* __restrict__ w1b, u16* __restrict__ w2b,
                       u16* __restrict__ wrb, u16* __restrict__ wxb,
                       float* __restrict__ bperm, u16* __restrict__ whb,
                       float* __restrict__ al1, float* __restrict__ be1,
                       float* __restrict__ al2, float* __restrict__ be2,
                       float* __restrict__ alr, float* __restrict__ ber)
{
  int tid = blockIdx.x * blockDim.x + threadIdx.x;
  int nth = gridDim.x * blockDim.x;
  for (int idx = tid; idx < 128 * 448; idx += nth) {
    int o = idx / 448, k = idx % 448;
    int kt = k >> 6, c = k & 63;
    w1b[idx] = f2bf(w1[(o * 64 + c) * 7 + kt]);
  }
  for (int idx = tid; idx < 96 * 384; idx += nth) {
    int o = idx / 384, k = idx % 384;
    int kk = k >> 7, c = k & 127;
    w2b[idx] = f2bf(w2[(o * 128 + c) * 3 + kk]);
  }
  for (int idx = tid; idx < 96 * 128; idx += nth) {
    wrb[idx] = f2bf(wr[idx]);
  }
  // wxb[row*96 + k] = bf16(wx[(g*96+ch)*96 + k] * gate_scale(g)), row = ch*4+g
  for (int idx = tid; idx < 384 * 96; idx += nth) {
    int row = idx / 96, k = idx % 96;
    int ch = row >> 2, g = row & 3;
    wxb[idx] = f2bf(wx[((size_t)(g * 96 + ch)) * 96 + k] * gate_scale(g));
  }
  // bperm[ch*4+g] = sbia[g*96+ch] * gate_scale(g)
  for (int c = tid; c < 384; c += nth) {
    int ch = c >> 2, g = c & 3;
    bperm[c] = sbia[g * 96 + ch] * gate_scale(g);
  }
  // whb[row*96 + k] = bf16(wh[(g*96+ch)*96 + k] * gate_scale(g)), row = ch*4+g
  for (int idx = tid; idx < 384 * 96; idx += nth) {
    int row = idx / 96, k = idx % 96;
    int ch = row >> 2, g = row & 3;
    whb[idx] = f2bf(wh[((size_t)(g * 96 + ch)) * 96 + k] * gate_scale(g));
  }
  for (int o = tid; o < 128; o += nth) {
    float a = g1[o] / sqrtf(v1[o] + 1e-5f);
    al1[o] = a; be1[o] = b1[o] + (cb1[o] - m1[o]) * a;
  }
  for (int o = tid; o < 96; o += nth) {
    float a = g2[o] / sqrtf(v2[o] + 1e-5f);
    al2[o] = a; be2[o] = b2[o] + (cb2[o] - m2[o]) * a;
    float ar = gr[o] / sqrtf(vr[o] + 1e-5f);
    alr[o] = ar; ber[o] = br[o] + (cbr[o] - mr[o]) * ar;
  }
}

// ---------------- K1: conv1 MFMA implicit GEMM (unchanged) ----------------
__launch_bounds__(256, 2)
__global__ void k_conv1(const float* __restrict__ x, const u16* __restrict__ w1b,
                        const float* __restrict__ al1, const float* __restrict__ be1,
                        u16* __restrict__ out1)
{
  __shared__ __align__(16) u16 xs[134 * 72];
  int tid = threadIdx.x;
  int b = blockIdx.y;
  int t0 = blockIdx.x * 128;
  const float* xb = x + (size_t)b * Tt * Cin;

  for (int idx = tid; idx < 134 * 16; idx += 256) {
    int row = idx >> 4, c4 = (idx & 15) << 2;
    int gt = t0 - 3 + row;
    float4 v = make_float4(0.f, 0.f, 0.f, 0.f);
    if (gt >= 0 && gt < Tt) v = *(const float4*)(xb + (size_t)gt * 64 + c4);
    ushort4 s;
    s.x = f2bf(v.x); s.y = f2bf(v.y); s.z = f2bf(v.z); s.w = f2bf(v.w);
    *(ushort4*)(xs + row * 72 + c4) = s;
  }
  __syncthreads();

  int l = tid & 63;
  int wid = tid >> 6;
  int wm = wid >> 1, wn = wid & 1;
  int lr = l & 15, g = l >> 4;

  f32x4 acc[4][4];
#pragma unroll
  for (int i = 0; i < 4; i++)
#pragma unroll
    for (int j = 0; j < 4; j++) acc[i][j] = (f32x4){0.f, 0.f, 0.f, 0.f};

  const u16* wbase = w1b + (size_t)(wn * 64 + lr) * 448;

  for (int s = 0; s < 14; ++s) {
    int kt = s >> 1;
    int cofs = ((s & 1) << 5) + (g << 3);
    const u16* xrow = xs + (wm * 64 + lr + kt) * 72 + cofs;
    bf16x8 a0 = *(const bf16x8*)(xrow);
    bf16x8 a1 = *(const bf16x8*)(xrow + 16 * 72);
    bf16x8 a2 = *(const bf16x8*)(xrow + 32 * 72);
    bf16x8 a3 = *(const bf16x8*)(xrow + 48 * 72);
    int ko = (s << 5) + (g << 3);
    bf16x8 b0 = *(const bf16x8*)(wbase + ko);
    bf16x8 b1 = *(const bf16x8*)(wbase + 16 * 448 + ko);
    bf16x8 b2 = *(const bf16x8*)(wbase + 32 * 448 + ko);
    bf16x8 b3 = *(const bf16x8*)(wbase + 48 * 448 + ko);
    acc[0][0] = MFMA16(a0, b0, acc[0][0]);
    acc[0][1] = MFMA16(a0, b1, acc[0][1]);
    acc[0][2] = MFMA16(a0, b2, acc[0][2]);
    acc[0][3] = MFMA16(a0, b3, acc[0][3]);
    acc[1][0] = MFMA16(a1, b0, acc[1][0]);
    acc[1][1] = MFMA16(a1, b1, acc[1][1]);
    acc[1][2] = MFMA16(a1, b2, acc[1][2]);
    acc[1][3] = MFMA16(a1, b3, acc[1][3]);
    acc[2][0] = MFMA16(a2, b0, acc[2][0]);
    acc[2][1] = MFMA16(a2, b1, acc[2][1]);
    acc[2][2] = MFMA16(a2, b2, acc[2][2]);
    acc[2][3] = MFMA16(a2, b3, acc[2][3]);
    acc[3][0] = MFMA16(a3, b0, acc[3][0]);
    acc[3][1] = MFMA16(a3, b1, acc[3][1]);
    acc[3][2] = MFMA16(a3, b2, acc[3][2]);
    acc[3][3] = MFMA16(a3, b3, acc[3][3]);
  }

  int colb = wn * 64 + lr;
  int rowb = t0 + wm * 64 + (l >> 4) * 4;
#pragma unroll
  for (int nf = 0; nf < 4; nf++) {
    int col = colb + nf * 16;
    float A = al1[col], Bt = be1[col];
#pragma unroll
    for (int mf = 0; mf < 4; mf++) {
      int row = rowb + mf * 16;
#pragma unroll
      for (int r = 0; r < 4; r++) {
        float v = acc[mf][nf][r];
        v = fmaxf(v * A + Bt, 0.f);
        out1[((size_t)b * Tt + row + r) * 128 + col] = f2bf(v);
      }
    }
  }
}

// ---------------- K2: conv2 MFMA implicit GEMM + fused residual -> seqb bf16 (unchanged) ----------------
__launch_bounds__(256, 4)
__global__ void k_conv2(const u16* __restrict__ out1, const u16* __restrict__ w2b,
                        const u16* __restrict__ wrb,
                        const float* __restrict__ al2, const float* __restrict__ be2,
                        const float* __restrict__ alr, const float* __restrict__ ber,
                        u16* __restrict__ seqb)
{
  int tid = threadIdx.x;
  int b = blockIdx.y;
  int t20 = blockIdx.x * 64;
  int l = tid & 63;
  int wid = tid >> 6;
  int wm = wid >> 1, wn = wid & 1;    // wave tile 32 x 48
  int lr = l & 15, g = l >> 4;

  f32x4 acc[2][3], accr[2][3];
#pragma unroll
  for (int i = 0; i < 2; i++)
#pragma unroll
    for (int j = 0; j < 3; j++) {
      acc[i][j] = (f32x4){0.f, 0.f, 0.f, 0.f};
      accr[i][j] = (f32x4){0.f, 0.f, 0.f, 0.f};
    }

  const u16* ob = out1 + (size_t)b * Tt * 128;
  int colb = wn * 48 + lr;

#pragma unroll
  for (int f = 0; f < 12; f++) {
    int kk = f >> 2;
    int c = ((f & 3) << 5) + (g << 3);
    bf16x8 a[2];
#pragma unroll
    for (int mf = 0; mf < 2; mf++) {
      int t2 = t20 + wm * 32 + mf * 16 + lr;
      int gt = 4 * t2 + kk - 1;
      if (gt >= 0)
        a[mf] = *(const bf16x8*)(ob + (size_t)gt * 128 + c);
      else
        a[mf] = (bf16x8){0, 0, 0, 0, 0, 0, 0, 0};
    }
#pragma unroll
    for (int nf = 0; nf < 3; nf++) {
      int col = colb + nf * 16;
      bf16x8 bb = *(const bf16x8*)(w2b + (size_t)col * 384 + (f << 5) + (g << 3));
      acc[0][nf] = MFMA16(a[0], bb, acc[0][nf]);
      acc[1][nf] = MFMA16(a[1], bb, acc[1][nf]);
    }
    if (kk == 1) {
#pragma unroll
      for (int nf = 0; nf < 3; nf++) {
        int col = colb + nf * 16;
        bf16x8 br = *(const bf16x8*)(wrb + (size_t)col * 128 + ((f & 3) << 5) + (g << 3));
        accr[0][nf] = MFMA16(a[0], br, accr[0][nf]);
        accr[1][nf] = MFMA16(a[1], br, accr[1][nf]);
      }
    }
  }

  int rowb = t20 + wm * 32 + (l >> 4) * 4;
#pragma unroll
  for (int nf = 0; nf < 3; nf++) {
    int col = colb + nf * 16;
    float A = al2[col], Bt = be2[col];
    float Ar = alr[col], Br = ber[col];
#pragma unroll
    for (int mf = 0; mf < 2; mf++) {
      int row = rowb + mf * 16;
#pragma unroll
      for (int r = 0; r < 4; r++) {
        float v = fmaxf(acc[mf][nf][r] * A + Bt, 0.f) + accr[mf][nf][r] * Ar + Br;
        seqb[((size_t)b * T2 + row + r) * 96 + col] = f2bf(v);
      }
    }
  }
}

// ---------------- K4: sLSTM v12 — producer/consumer + time-batched px ----------------
// 512 threads = 8 waves, one block per batch (64 blocks).
// Waves 0-3 (consumers): recurrence for channels [24w,24w+24), wh frags in
//   72 VGPR. Per step: px C-in (6xb128 broadcast) + h (3xb128) -> 18 MFMA ->
//   cndmask select -> gates -> h bf16 write. s_setprio(1) around the body.
// Waves 4-7 (producers): every 16 steps, ONE 18-MFMA batch computes
//   px(t+16..t+31) for rows [96pw,96pw+96) (MFMA B-col = timestep), written
//   to a 32-slot ring: slot (t+16+lr)&31. Concurrent reads touch slots
//   (t..t+15)&31 — disjoint; each write is >=16 barriers ahead of its read.
// One __syncthreads per step (both branches execute 1 prologue + T2 barriers).
__launch_bounds__(512, 1)
__global__ void k_slstm(const u16* __restrict__ seqb, const u16* __restrict__ whb,
                        const u16* __restrict__ wxb, const float* __restrict__ bperm,
                        float* __restrict__ hsum)
{
  __shared__ __align__(16) float pxring[32][388];
  __shared__ __align__(16) u16 hbufB[2][96];
  int tid = threadIdx.x;
  int b = blockIdx.x;
  int w = tid >> 6;          // 0..7
  int l = tid & 63;
  int grp = l >> 4, lr = l & 15;

  if (w < 4) {
    // ---------------- consumer ----------------
    bf16x8 af[6][3];
#pragma unroll
    for (int m = 0; m < 6; m++) {
      const u16* wrow = whb + (size_t)(96 * w + 16 * m + lr) * 96 + grp * 8;
#pragma unroll
      for (int kt = 0; kt < 3; kt++) af[m][kt] = *(const bf16x8*)(wrow + kt * 32);
    }
    bool gl = (lr < 6);
    int ch = 24 * w + 4 * lr + grp;
    float cS = 0.f, nS = 0.f, mS = 0.f, hs = 0.f;
    if (tid < 96) hbufB[0][tid] = 0;
    __syncthreads();

    int p = 0;
    for (int t = 0; t < T2; t++) {
      __builtin_amdgcn_s_setprio(1);
      const float* pxs = &pxring[t & 31][96 * w];
      const u16* hb = hbufB[p] + grp * 8;
      bf16x8 h0 = *(const bf16x8*)(hb);
      bf16x8 h1 = *(const bf16x8*)(hb + 32);
      bf16x8 h2 = *(const bf16x8*)(hb + 64);
      f32x4 acc[6];
#pragma unroll
      for (int m = 0; m < 6; m++) {
        f32x4 pc = *(const f32x4*)(pxs + 16 * m + 4 * grp);
        acc[m] = MFMA16(af[m][0], h0, pc);
        acc[m] = MFMA16(af[m][1], h1, acc[m]);
        acc[m] = MFMA16(af[m][2], h2, acc[m]);
      }
      f32x4 x01 = (lr & 1) ? acc[1] : acc[0];
      f32x4 x23 = (lr & 1) ? acc[3] : acc[2];
      f32x4 x45 = (lr & 1) ? acc[5] : acc[4];
      f32x4 y0 = (lr & 2) ? x23 : x01;
      f32x4 pa = (lr & 4) ? x45 : y0;
      if (gl) {
        float zp = pa[0], ip = pa[1], fp = pa[2], op = pa[3];
        float zc = fminf(fmaxf(zp, -86.f), 86.f);
        float ez = exp2f(zc);
        float z = 1.f - 2.f * __builtin_amdgcn_rcpf(ez + 1.f);
        float oc = fminf(fmaxf(op, -60.f), 60.f);
        float o = __builtin_amdgcn_rcpf(1.f + exp2f(-oc));
        float mn = fmaxf(fp + mS, ip);
        float iv = exp2f(ip - mn);
        float fv = exp2f(fp + mS - mn);
        cS = fv * cS + iv * z;
        nS = fv * nS + iv;
        mS = mn;
        float h = o * cS * __builtin_amdgcn_rcpf(fmaxf(nS, 1.f));
        hs += h;
        hbufB[p ^ 1][ch] = f2bf(h);
      }
      __builtin_amdgcn_s_setprio(0);
      __syncthreads();
      p ^= 1;
    }
    if (gl) hsum[b * 96 + ch] = hs * (1.f / 1024.f);
  } else {
    // ---------------- producer (time-batched px) ----------------
    int pw = w - 4;
    bf16x8 wf[6][3];
#pragma unroll
    for (int m = 0; m < 6; m++) {
      const u16* xrow = wxb + (size_t)(96 * pw + 16 * m + lr) * 96 + grp * 8;
#pragma unroll
      for (int kt = 0; kt < 3; kt++) wf[m][kt] = *(const bf16x8*)(xrow + kt * 32);
    }
    f32x4 bias6[6];
#pragma unroll
    for (int m = 0; m < 6; m++)
      bias6[m] = *(const f32x4*)(bperm + 96 * pw + 16 * m + 4 * grp);

    const u16* sqB = seqb + (size_t)b * T2 * 96 + grp * 8;

    // prologue: fill slots 0..15 with px(0..15); B col = timestep lr
    {
      const u16* sp_ = sqB + (size_t)lr * 96;
      bf16x8 s0 = *(const bf16x8*)(sp_);
      bf16x8 s1 = *(const bf16x8*)(sp_ + 32);
      bf16x8 s2 = *(const bf16x8*)(sp_ + 64);
      f32x4 pc[6];
#pragma unroll
      for (int m = 0; m < 6; m++) {
        pc[m] = MFMA16(wf[m][0], s0, bias6[m]);
        pc[m] = MFMA16(wf[m][1], s1, pc[m]);
        pc[m] = MFMA16(wf[m][2], s2, pc[m]);
      }
#pragma unroll
      for (int m = 0; m < 6; m++)
        *(f32x4*)(&pxring[lr][96 * pw + 16 * m + 4 * grp]) = pc[m];
    }
    // prefetch seq for window 0 (timesteps 16+lr)
    bf16x8 s0, s1, s2;
    {
      int ts = 16 + lr; if (ts > T2 - 1) ts = T2 - 1;
      const u16* sp_ = sqB + (size_t)ts * 96;
      s0 = *(const bf16x8*)(sp_);
      s1 = *(const bf16x8*)(sp_ + 32);
      s2 = *(const bf16x8*)(sp_ + 64);
    }
    __syncthreads();

    for (int t = 0; t < T2; t++) {
      if (((t & 15) == 0) && (t + 16 < T2)) {
        f32x4 pacc[6];
#pragma unroll
        for (int m = 0; m < 6; m++) {
          pacc[m] = MFMA16(wf[m][0], s0, bias6[m]);
          pacc[m] = MFMA16(wf[m][1], s1, pacc[m]);
          pacc[m] = MFMA16(wf[m][2], s2, pacc[m]);
        }
        int slot = (t + 16 + lr) & 31;
#pragma unroll
        for (int m = 0; m < 6; m++)
          *(f32x4*)(&pxring[slot][96 * pw + 16 * m + 4 * grp]) = pacc[m];
        int ts = t + 32 + lr; if (ts > T2 - 1) ts = T2 - 1;
        const u16* sp_ = sqB + (size_t)ts * 96;
        s0 = *(const bf16x8*)(sp_);
        s1 = *(const bf16x8*)(sp_ + 32);
        s2 = *(const bf16x8*)(sp_ + 64);
      }
      __syncthreads();
    }
  }
}

// ---------------- K5: head (unchanged) ----------------
__launch_bounds__(128)
__global__ void k_head(const float* __restrict__ hsum, const float* __restrict__ fc1w,
                       const float* __restrict__ fc1b, const float* __restrict__ fc2w,
                       const float* __restrict__ fc2b, float* __restrict__ out)
{
  __shared__ float p[96];
  __shared__ float z1[128];
  int tid = threadIdx.x, b = blockIdx.x;
  if (tid < 96) p[tid] = hsum[b * 96 + tid];
  __syncthreads();
  {
    float a = fc1b[tid];
    const float* wr = fc1w + tid * 96;
    for (int h = 0; h < 96; h++) a += p[h] * wr[h];
    z1[tid] = fmaxf(a, 0.f);
  }
  __syncthreads();
  if (tid < NC) {
    float a = fc2b[tid];
    const float* wr = fc2w + tid * 128;
    for (int j = 0; j < 128; j++) a += z1[j] * wr[j];
    out[b * NC + tid] = a;
  }
}

extern "C" void kernel_launch(void* const* d_in, const int* in_sizes, int n_in,
                              void* d_out, int out_size, void* d_ws, size_t ws_size,
                              hipStream_t stream)
{
  const float* x    = (const float*)d_in[0];
  const float* w1   = (const float*)d_in[1];
  const float* cb1  = (const float*)d_in[2];
  const float* g1   = (const float*)d_in[3];
  const float* b1   = (const float*)d_in[4];
  const float* m1   = (const float*)d_in[5];
  const float* v1   = (const float*)d_in[6];
  const float* w2   = (const float*)d_in[7];
  const float* cb2  = (const float*)d_in[8];
  const float* g2   = (const float*)d_in[9];
  const float* b2   = (const float*)d_in[10];
  const float* m2   = (const float*)d_in[11];
  const float* v2   = (const float*)d_in[12];
  const float* wr   = (const float*)d_in[13];
  const float* cbr  = (const float*)d_in[14];
  const float* gr   = (const float*)d_in[15];
  const float* br   = (const float*)d_in[16];
  const float* mr   = (const float*)d_in[17];
  const float* vr   = (const float*)d_in[18];
  const float* wx   = (const float*)d_in[19];
  const float* wh   = (const float*)d_in[20];
  const float* sbia = (const float*)d_in[21];
  const float* fc1w = (const float*)d_in[22];
  const float* fc1b = (const float*)d_in[23];
  const float* fc2w = (const float*)d_in[24];
  const float* fc2b = (const float*)d_in[25];

  char* ws = (char*)d_ws;
  size_t off = 0;
  auto alloc = [&](size_t bytes) -> void* {
    void* p = (void*)(ws + off);
    off = (off + bytes + 255) & ~((size_t)255);
    return p;
  };
  u16*   out1 = (u16*)  alloc((size_t)Bz * Tt * K1c * 2);   // 67.1 MB
  u16*   seqb = (u16*)  alloc((size_t)Bz * T2 * Hh * 2);    // 12.6 MB
  u16*   w1b  = (u16*)  alloc(448 * 128 * 2);
  u16*   w2b  = (u16*)  alloc(96 * 384 * 2);
  u16*   wrb  = (u16*)  alloc(96 * 128 * 2);
  u16*   wxb  = (u16*)  alloc(384 * 96 * 2);
  float* bperm= (float*)alloc(384 * 4);
  u16*   whb  = (u16*)  alloc(384 * 96 * 2);
  float* al1  = (float*)alloc(128 * 4);
  float* be1  = (float*)alloc(128 * 4);
  float* al2  = (float*)alloc(96 * 4);
  float* be2  = (float*)alloc(96 * 4);
  float* alr  = (float*)alloc(96 * 4);
  float* ber  = (float*)alloc(96 * 4);
  float* hsum = (float*)alloc((size_t)Bz * Hh * 4);
  (void)ws_size; (void)in_sizes; (void)n_in; (void)out_size;

  k_prep<<<dim3(224), dim3(256), 0, stream>>>(
      w1, cb1, g1, b1, m1, v1, w2, cb2, g2, b2, m2, v2,
      wr, cbr, gr, br, mr, vr, wx, sbia, wh,
      w1b, w2b, wrb, wxb, bperm, whb, al1, be1, al2, be2, alr, ber);

  k_conv1<<<dim3(Tt / 128, Bz), dim3(256), 0, stream>>>(x, w1b, al1, be1, out1);

  k_conv2<<<dim3(T2 / 64, Bz), dim3(256), 0, stream>>>(out1, w2b, wrb, al2, be2, alr, ber, seqb);

  k_slstm<<<dim3(Bz), dim3(512), 0, stream>>>(seqb, whb, wxb, bperm, hsum);

  k_head<<<dim3(Bz), dim3(128), 0, stream>>>(hsum, fc1w, fc1b, fc2w, fc2b, (float*)d_out);
}

// Round 16
// 512.753 us; speedup vs baseline: 1.2655x; 1.1039x over previous
//
#include <hip/hip_runtime.h>
#include <hip/hip_bf16.h>
#include <math.h>

typedef unsigned short u16;
typedef short bf16x8 __attribute__((ext_vector_type(8)));
typedef float f32x4 __attribute__((ext_vector_type(4)));

#define Bz 64
#define Tt 4096
#define Cin 64
#define K1c 128
#define Hh 96
#define T2 1024
#define G4 384
#define NC 109

#define MFMA16(a, b, c) __builtin_amdgcn_mfma_f32_16x16x32_bf16(a, b, c, 0, 0, 0)

__device__ __forceinline__ float bf2f(u16 v) {
  union { unsigned int u; float f; } x; x.u = ((unsigned int)v) << 16; return x.f;
}
__device__ __forceinline__ u16 f2bf(float f) {
  union { unsigned int u; float f; } x; x.f = f;
  unsigned int u = x.u;
  unsigned int r = u + 0x7fff + ((u >> 16) & 1);
  return (u16)(r >> 16);
}

// Gate scale: z-gate rows carry 2*log2(e), i/f/o rows carry log2(e).
__device__ __forceinline__ float gate_scale(int g) {
  const float L2E = 1.44269504f;
  return (g == 0) ? 2.f * L2E : L2E;
}

// ---------------- K0: weight packing + BN folding ----------------
__global__ void k_prep(const float* __restrict__ w1, const float* __restrict__ cb1,
                       const float* __restrict__ g1, const float* __restrict__ b1,
                       const float* __restrict__ m1, const float* __restrict__ v1,
                       const float* __restrict__ w2, const float* __restrict__ cb2,
                       const float* __restrict__ g2, const float* __restrict__ b2,
                       const float* __restrict__ m2, const float* __restrict__ v2,
                       const float* __restrict__ wr, const float* __restrict__ cbr,
                       const float* __restrict__ gr, const float* __restrict__ br,
                       const float* __restrict__ mr, const float* __restrict__ vr,
                       const float* __restrict__ wx, const float* __restrict__ sbia,
                       const float* __restrict__ wh,
                       u16* __restrict__ w1b, u16* __restrict__ w2b,
                       u16* __restrict__ wrb, u16* __restrict__ wxb,
                       float* __restrict__ bperm, u16* __restrict__ whb,
                       float* __restrict__ al1, float* __restrict__ be1,
                       float* __restrict__ al2, float* __restrict__ be2,
                       float* __restrict__ alr, float* __restrict__ ber)
{
  int tid = blockIdx.x * blockDim.x + threadIdx.x;
  int nth = gridDim.x * blockDim.x;
  for (int idx = tid; idx < 128 * 448; idx += nth) {
    int o = idx / 448, k = idx % 448;
    int kt = k >> 6, c = k & 63;
    w1b[idx] = f2bf(w1[(o * 64 + c) * 7 + kt]);
  }
  for (int idx = tid; idx < 96 * 384; idx += nth) {
    int o = idx / 384, k = idx % 384;
    int kk = k >> 7, c = k & 127;
    w2b[idx] = f2bf(w2[(o * 128 + c) * 3 + kk]);
  }
  for (int idx = tid; idx < 96 * 128; idx += nth) {
    wrb[idx] = f2bf(wr[idx]);
  }
  // wxb[row*96 + k] = bf16(wx[(g*96+ch)*96 + k] * gate_scale(g)), row = ch*4+g
  for (int idx = tid; idx < 384 * 96; idx += nth) {
    int row = idx / 96, k = idx % 96;
    int ch = row >> 2, g = row & 3;
    wxb[idx] = f2bf(wx[((size_t)(g * 96 + ch)) * 96 + k] * gate_scale(g));
  }
  // bperm[ch*4+g] = sbia[g*96+ch] * gate_scale(g)
  for (int c = tid; c < 384; c += nth) {
    int ch = c >> 2, g = c & 3;
    bperm[c] = sbia[g * 96 + ch] * gate_scale(g);
  }
  // whb[row*96 + k] = bf16(wh[(g*96+ch)*96 + k] * gate_scale(g)), row = ch*4+g
  for (int idx = tid; idx < 384 * 96; idx += nth) {
    int row = idx / 96, k = idx % 96;
    int ch = row >> 2, g = row & 3;
    whb[idx] = f2bf(wh[((size_t)(g * 96 + ch)) * 96 + k] * gate_scale(g));
  }
  for (int o = tid; o < 128; o += nth) {
    float a = g1[o] / sqrtf(v1[o] + 1e-5f);
    al1[o] = a; be1[o] = b1[o] + (cb1[o] - m1[o]) * a;
  }
  for (int o = tid; o < 96; o += nth) {
    float a = g2[o] / sqrtf(v2[o] + 1e-5f);
    al2[o] = a; be2[o] = b2[o] + (cb2[o] - m2[o]) * a;
    float ar = gr[o] / sqrtf(vr[o] + 1e-5f);
    alr[o] = ar; ber[o] = br[o] + (cbr[o] - mr[o]) * ar;
  }
}

// ---------------- K1: conv1 MFMA implicit GEMM (unchanged) ----------------
__launch_bounds__(256, 2)
__global__ void k_conv1(const float* __restrict__ x, const u16* __restrict__ w1b,
                        const float* __restrict__ al1, const float* __restrict__ be1,
                        u16* __restrict__ out1)
{
  __shared__ __align__(16) u16 xs[134 * 72];
  int tid = threadIdx.x;
  int b = blockIdx.y;
  int t0 = blockIdx.x * 128;
  const float* xb = x + (size_t)b * Tt * Cin;

  for (int idx = tid; idx < 134 * 16; idx += 256) {
    int row = idx >> 4, c4 = (idx & 15) << 2;
    int gt = t0 - 3 + row;
    float4 v = make_float4(0.f, 0.f, 0.f, 0.f);
    if (gt >= 0 && gt < Tt) v = *(const float4*)(xb + (size_t)gt * 64 + c4);
    ushort4 s;
    s.x = f2bf(v.x); s.y = f2bf(v.y); s.z = f2bf(v.z); s.w = f2bf(v.w);
    *(ushort4*)(xs + row * 72 + c4) = s;
  }
  __syncthreads();

  int l = tid & 63;
  int wid = tid >> 6;
  int wm = wid >> 1, wn = wid & 1;
  int lr = l & 15, g = l >> 4;

  f32x4 acc[4][4];
#pragma unroll
  for (int i = 0; i < 4; i++)
#pragma unroll
    for (int j = 0; j < 4; j++) acc[i][j] = (f32x4){0.f, 0.f, 0.f, 0.f};

  const u16* wbase = w1b + (size_t)(wn * 64 + lr) * 448;

  for (int s = 0; s < 14; ++s) {
    int kt = s >> 1;
    int cofs = ((s & 1) << 5) + (g << 3);
    const u16* xrow = xs + (wm * 64 + lr + kt) * 72 + cofs;
    bf16x8 a0 = *(const bf16x8*)(xrow);
    bf16x8 a1 = *(const bf16x8*)(xrow + 16 * 72);
    bf16x8 a2 = *(const bf16x8*)(xrow + 32 * 72);
    bf16x8 a3 = *(const bf16x8*)(xrow + 48 * 72);
    int ko = (s << 5) + (g << 3);
    bf16x8 b0 = *(const bf16x8*)(wbase + ko);
    bf16x8 b1 = *(const bf16x8*)(wbase + 16 * 448 + ko);
    bf16x8 b2 = *(const bf16x8*)(wbase + 32 * 448 + ko);
    bf16x8 b3 = *(const bf16x8*)(wbase + 48 * 448 + ko);
    acc[0][0] = MFMA16(a0, b0, acc[0][0]);
    acc[0][1] = MFMA16(a0, b1, acc[0][1]);
    acc[0][2] = MFMA16(a0, b2, acc[0][2]);
    acc[0][3] = MFMA16(a0, b3, acc[0][3]);
    acc[1][0] = MFMA16(a1, b0, acc[1][0]);
    acc[1][1] = MFMA16(a1, b1, acc[1][1]);
    acc[1][2] = MFMA16(a1, b2, acc[1][2]);
    acc[1][3] = MFMA16(a1, b3, acc[1][3]);
    acc[2][0] = MFMA16(a2, b0, acc[2][0]);
    acc[2][1] = MFMA16(a2, b1, acc[2][1]);
    acc[2][2] = MFMA16(a2, b2, acc[2][2]);
    acc[2][3] = MFMA16(a2, b3, acc[2][3]);
    acc[3][0] = MFMA16(a3, b0, acc[3][0]);
    acc[3][1] = MFMA16(a3, b1, acc[3][1]);
    acc[3][2] = MFMA16(a3, b2, acc[3][2]);
    acc[3][3] = MFMA16(a3, b3, acc[3][3]);
  }

  int colb = wn * 64 + lr;
  int rowb = t0 + wm * 64 + (l >> 4) * 4;
#pragma unroll
  for (int nf = 0; nf < 4; nf++) {
    int col = colb + nf * 16;
    float A = al1[col], Bt = be1[col];
#pragma unroll
    for (int mf = 0; mf < 4; mf++) {
      int row = rowb + mf * 16;
#pragma unroll
      for (int r = 0; r < 4; r++) {
        float v = acc[mf][nf][r];
        v = fmaxf(v * A + Bt, 0.f);
        out1[((size_t)b * Tt + row + r) * 128 + col] = f2bf(v);
      }
    }
  }
}

// ---------------- K2: conv2 MFMA implicit GEMM + fused residual -> seqb bf16 (unchanged) ----------------
__launch_bounds__(256, 4)
__global__ void k_conv2(const u16* __restrict__ out1, const u16* __restrict__ w2b,
                        const u16* __restrict__ wrb,
                        const float* __restrict__ al2, const float* __restrict__ be2,
                        const float* __restrict__ alr, const float* __restrict__ ber,
                        u16* __restrict__ seqb)
{
  int tid = threadIdx.x;
  int b = blockIdx.y;
  int t20 = blockIdx.x * 64;
  int l = tid & 63;
  int wid = tid >> 6;
  int wm = wid >> 1, wn = wid & 1;    // wave tile 32 x 48
  int lr = l & 15, g = l >> 4;

  f32x4 acc[2][3], accr[2][3];
#pragma unroll
  for (int i = 0; i < 2; i++)
#pragma unroll
    for (int j = 0; j < 3; j++) {
      acc[i][j] = (f32x4){0.f, 0.f, 0.f, 0.f};
      accr[i][j] = (f32x4){0.f, 0.f, 0.f, 0.f};
    }

  const u16* ob = out1 + (size_t)b * Tt * 128;
  int colb = wn * 48 + lr;

#pragma unroll
  for (int f = 0; f < 12; f++) {
    int kk = f >> 2;
    int c = ((f & 3) << 5) + (g << 3);
    bf16x8 a[2];
#pragma unroll
    for (int mf = 0; mf < 2; mf++) {
      int t2 = t20 + wm * 32 + mf * 16 + lr;
      int gt = 4 * t2 + kk - 1;
      if (gt >= 0)
        a[mf] = *(const bf16x8*)(ob + (size_t)gt * 128 + c);
      else
        a[mf] = (bf16x8){0, 0, 0, 0, 0, 0, 0, 0};
    }
#pragma unroll
    for (int nf = 0; nf < 3; nf++) {
      int col = colb + nf * 16;
      bf16x8 bb = *(const bf16x8*)(w2b + (size_t)col * 384 + (f << 5) + (g << 3));
      acc[0][nf] = MFMA16(a[0], bb, acc[0][nf]);
      acc[1][nf] = MFMA16(a[1], bb, acc[1][nf]);
    }
    if (kk == 1) {
#pragma unroll
      for (int nf = 0; nf < 3; nf++) {
        int col = colb + nf * 16;
        bf16x8 br = *(const bf16x8*)(wrb + (size_t)col * 128 + ((f & 3) << 5) + (g << 3));
        accr[0][nf] = MFMA16(a[0], br, accr[0][nf]);
        accr[1][nf] = MFMA16(a[1], br, accr[1][nf]);
      }
    }
  }

  int rowb = t20 + wm * 32 + (l >> 4) * 4;
#pragma unroll
  for (int nf = 0; nf < 3; nf++) {
    int col = colb + nf * 16;
    float A = al2[col], Bt = be2[col];
    float Ar = alr[col], Br = ber[col];
#pragma unroll
    for (int mf = 0; mf < 2; mf++) {
      int row = rowb + mf * 16;
#pragma unroll
      for (int r = 0; r < 4; r++) {
        float v = fmaxf(acc[mf][nf][r] * A + Bt, 0.f) + accr[mf][nf][r] * Ar + Br;
        seqb[((size_t)b * T2 + row + r) * 96 + col] = f2bf(v);
      }
    }
  }
}

// ---------------- K4: sLSTM v13 — v12 + px register double-buffer ----------------
// 512 threads = 8 waves, one block per batch (64 blocks).
// Waves 0-3 (consumers): per step issue 3 h ds_reads FIRST, then 6 px reads
//   for slot t+1 (consumed next step from registers). MFMA C-in = px regs
//   prefetched last step -> MFMA waits only on h (fine-grained lgkmcnt).
// Waves 4-7 (producers): every 16 steps one 18-MFMA batch computes
//   px(t+16..t+31) (MFMA B-col = timestep) into 32-slot ring. Slot t+1 is
//   always >=15 steps old when prefetched -> race-free.
// One __syncthreads per step; setprio(1) around consumer body.
__launch_bounds__(512, 1)
__global__ void k_slstm(const u16* __restrict__ seqb, const u16* __restrict__ whb,
                        const u16* __restrict__ wxb, const float* __restrict__ bperm,
                        float* __restrict__ hsum)
{
  __shared__ __align__(16) float pxring[32][388];
  __shared__ __align__(16) u16 hbufB[2][96];
  int tid = threadIdx.x;
  int b = blockIdx.x;
  int w = tid >> 6;          // 0..7
  int l = tid & 63;
  int grp = l >> 4, lr = l & 15;

  if (w < 4) {
    // ---------------- consumer ----------------
    bf16x8 af[6][3];
#pragma unroll
    for (int m = 0; m < 6; m++) {
      const u16* wrow = whb + (size_t)(96 * w + 16 * m + lr) * 96 + grp * 8;
#pragma unroll
      for (int kt = 0; kt < 3; kt++) af[m][kt] = *(const bf16x8*)(wrow + kt * 32);
    }
    bool gl = (lr < 6);
    int ch = 24 * w + 4 * lr + grp;
    float cS = 0.f, nS = 0.f, mS = 0.f, hs = 0.f;
    if (tid < 96) hbufB[0][tid] = 0;
    __syncthreads();
    // px for step 0 (slot 0 filled by producer prologue before this barrier...
    // NOTE: producers fill slots 0..15 BEFORE the first barrier; the barrier
    // above is the consumer's zero-init sync; a second barrier below aligns
    // with the producer prologue completion.
    __syncthreads();
    f32x4 pxA[6], pxB[6];
#pragma unroll
    for (int m = 0; m < 6; m++)
      pxA[m] = *(const f32x4*)(&pxring[0][96 * w + 16 * m + 4 * grp]);

    int p = 0;
#define CONS_STEP(PXC, PXN, TT)                                                \
  {                                                                            \
    __builtin_amdgcn_s_setprio(1);                                             \
    const u16* hb_ = hbufB[p] + grp * 8;                                       \
    bf16x8 h0_ = *(const bf16x8*)(hb_);                                        \
    bf16x8 h1_ = *(const bf16x8*)(hb_ + 32);                                   \
    bf16x8 h2_ = *(const bf16x8*)(hb_ + 64);                                   \
    const float* pxs_ = &pxring[((TT) + 1) & 31][96 * w];                      \
    _Pragma("unroll")                                                          \
    for (int m = 0; m < 6; m++)                                                \
      PXN[m] = *(const f32x4*)(pxs_ + 16 * m + 4 * grp);                       \
    f32x4 acc_[6];                                                             \
    _Pragma("unroll")                                                          \
    for (int m = 0; m < 6; m++) {                                              \
      acc_[m] = MFMA16(af[m][0], h0_, PXC[m]);                                 \
      acc_[m] = MFMA16(af[m][1], h1_, acc_[m]);                                \
      acc_[m] = MFMA16(af[m][2], h2_, acc_[m]);                                \
    }                                                                          \
    f32x4 x01_ = (lr & 1) ? acc_[1] : acc_[0];                                 \
    f32x4 x23_ = (lr & 1) ? acc_[3] : acc_[2];                                 \
    f32x4 x45_ = (lr & 1) ? acc_[5] : acc_[4];                                 \
    f32x4 y0_ = (lr & 2) ? x23_ : x01_;                                        \
    f32x4 pa_ = (lr & 4) ? x45_ : y0_;                                         \
    if (gl) {                                                                  \
      float zp_ = pa_[0], ip_ = pa_[1], fp_ = pa_[2], op_ = pa_[3];            \
      float zc_ = fminf(fmaxf(zp_, -86.f), 86.f);                              \
      float ez_ = exp2f(zc_);                                                  \
      float z_ = 1.f - 2.f * __builtin_amdgcn_rcpf(ez_ + 1.f);                 \
      float oc_ = fminf(fmaxf(op_, -60.f), 60.f);                              \
      float o_ = __builtin_amdgcn_rcpf(1.f + exp2f(-oc_));                     \
      float mn_ = fmaxf(fp_ + mS, ip_);                                        \
      float iv_ = exp2f(ip_ - mn_);                                            \
      float fv_ = exp2f(fp_ + mS - mn_);                                       \
      cS = fv_ * cS + iv_ * z_;                                                \
      nS = fv_ * nS + iv_;                                                     \
      mS = mn_;                                                                \
      float h_ = o_ * cS * __builtin_amdgcn_rcpf(fmaxf(nS, 1.f));              \
      hs += h_;                                                                \
      hbufB[p ^ 1][ch] = f2bf(h_);                                             \
    }                                                                          \
    __builtin_amdgcn_s_setprio(0);                                             \
    __syncthreads();                                                           \
    p ^= 1;                                                                    \
  }

    for (int t = 0; t < T2; t += 2) {
      CONS_STEP(pxA, pxB, t);
      CONS_STEP(pxB, pxA, t + 1);
    }
#undef CONS_STEP
    if (gl) hsum[b * 96 + ch] = hs * (1.f / 1024.f);
  } else {
    // ---------------- producer (time-batched px) ----------------
    int pw = w - 4;
    bf16x8 wf[6][3];
#pragma unroll
    for (int m = 0; m < 6; m++) {
      const u16* xrow = wxb + (size_t)(96 * pw + 16 * m + lr) * 96 + grp * 8;
#pragma unroll
      for (int kt = 0; kt < 3; kt++) wf[m][kt] = *(const bf16x8*)(xrow + kt * 32);
    }
    f32x4 bias6[6];
#pragma unroll
    for (int m = 0; m < 6; m++)
      bias6[m] = *(const f32x4*)(bperm + 96 * pw + 16 * m + 4 * grp);

    const u16* sqB = seqb + (size_t)b * T2 * 96 + grp * 8;

    __syncthreads();  // matches consumer zero-init barrier
    // prologue: fill slots 0..15 with px(0..15); B col = timestep lr
    {
      const u16* sp_ = sqB + (size_t)lr * 96;
      bf16x8 s0 = *(const bf16x8*)(sp_);
      bf16x8 s1 = *(const bf16x8*)(sp_ + 32);
      bf16x8 s2 = *(const bf16x8*)(sp_ + 64);
      f32x4 pc[6];
#pragma unroll
      for (int m = 0; m < 6; m++) {
        pc[m] = MFMA16(wf[m][0], s0, bias6[m]);
        pc[m] = MFMA16(wf[m][1], s1, pc[m]);
        pc[m] = MFMA16(wf[m][2], s2, pc[m]);
      }
#pragma unroll
      for (int m = 0; m < 6; m++)
        *(f32x4*)(&pxring[lr][96 * pw + 16 * m + 4 * grp]) = pc[m];
    }
    // prefetch seq for window 0 (timesteps 16+lr)
    bf16x8 s0, s1, s2;
    {
      int ts = 16 + lr; if (ts > T2 - 1) ts = T2 - 1;
      const u16* sp_ = sqB + (size_t)ts * 96;
      s0 = *(const bf16x8*)(sp_);
      s1 = *(const bf16x8*)(sp_ + 32);
      s2 = *(const bf16x8*)(sp_ + 64);
    }
    __syncthreads();  // slots 0..15 visible; consumer reads px slot 0 after this

    for (int t = 0; t < T2; t++) {
      if (((t & 15) == 0) && (t + 16 < T2)) {
        f32x4 pacc[6];
#pragma unroll
        for (int m = 0; m < 6; m++) {
          pacc[m] = MFMA16(wf[m][0], s0, bias6[m]);
          pacc[m] = MFMA16(wf[m][1], s1, pacc[m]);
          pacc[m] = MFMA16(wf[m][2], s2, pacc[m]);
        }
        int slot = (t + 16 + lr) & 31;
#pragma unroll
        for (int m = 0; m < 6; m++)
          *(f32x4*)(&pxring[slot][96 * pw + 16 * m + 4 * grp]) = pacc[m];
        int ts = t + 32 + lr; if (ts > T2 - 1) ts = T2 - 1;
        const u16* sp_ = sqB + (size_t)ts * 96;
        s0 = *(const bf16x8*)(sp_);
        s1 = *(const bf16x8*)(sp_ + 32);
        s2 = *(const bf16x8*)(sp_ + 64);
      }
      __syncthreads();
    }
  }
}

// ---------------- K5: head (unchanged) ----------------
__launch_bounds__(128)
__global__ void k_head(const float* __restrict__ hsum, const float* __restrict__ fc1w,
                       const float* __restrict__ fc1b, const float* __restrict__ fc2w,
                       const float* __restrict__ fc2b, float* __restrict__ out)
{
  __shared__ float p[96];
  __shared__ float z1[128];
  int tid = threadIdx.x, b = blockIdx.x;
  if (tid < 96) p[tid] = hsum[b * 96 + tid];
  __syncthreads();
  {
    float a = fc1b[tid];
    const float* wr = fc1w + tid * 96;
    for (int h = 0; h < 96; h++) a += p[h] * wr[h];
    z1[tid] = fmaxf(a, 0.f);
  }
  __syncthreads();
  if (tid < NC) {
    float a = fc2b[tid];
    const float* wr = fc2w + tid * 128;
    for (int j = 0; j < 128; j++) a += z1[j] * wr[j];
    out[b * NC + tid] = a;
  }
}

extern "C" void kernel_launch(void* const* d_in, const int* in_sizes, int n_in,
                              void* d_out, int out_size, void* d_ws, size_t ws_size,
                              hipStream_t stream)
{
  const float* x    = (const float*)d_in[0];
  const float* w1   = (const float*)d_in[1];
  const float* cb1  = (const float*)d_in[2];
  const float* g1   = (const float*)d_in[3];
  const float* b1   = (const float*)d_in[4];
  const float* m1   = (const float*)d_in[5];
  const float* v1   = (const float*)d_in[6];
  const float* w2   = (const float*)d_in[7];
  const float* cb2  = (const float*)d_in[8];
  const float* g2   = (const float*)d_in[9];
  const float* b2   = (const float*)d_in[10];
  const float* m2   = (const float*)d_in[11];
  const float* v2   = (const float*)d_in[12];
  const float* wr   = (const float*)d_in[13];
  const float* cbr  = (const float*)d_in[14];
  const float* gr   = (const float*)d_in[15];
  const float* br   = (const float*)d_in[16];
  const float* mr   = (const float*)d_in[17];
  const float* vr   = (const float*)d_in[18];
  const float* wx   = (const float*)d_in[19];
  const float* wh   = (const float*)d_in[20];
  const float* sbia = (const float*)d_in[21];
  const float* fc1w = (const float*)d_in[22];
  const float* fc1b = (const float*)d_in[23];
  const float* fc2w = (const float*)d_in[24];
  const float* fc2b = (const float*)d_in[25];

  char* ws = (char*)d_ws;
  size_t off = 0;
  auto alloc = [&](size_t bytes) -> void* {
    void* p = (void*)(ws + off);
    off = (off + bytes + 255) & ~((size_t)255);
    return p;
  };
  u16*   out1 = (u16*)  alloc((size_t)Bz * Tt * K1c * 2);   // 67.1 MB
  u16*   seqb = (u16*)  alloc((size_t)Bz * T2 * Hh * 2);    // 12.6 MB
  u16*   w1b  = (u16*)  alloc(448 * 128 * 2);
  u16*   w2b  = (u16*)  alloc(96 * 384 * 2);
  u16*   wrb  = (u16*)  alloc(96 * 128 * 2);
  u16*   wxb  = (u16*)  alloc(384 * 96 * 2);
  float* bperm= (float*)alloc(384 * 4);
  u16*   whb  = (u16*)  alloc(384 * 96 * 2);
  float* al1  = (float*)alloc(128 * 4);
  float* be1  = (float*)alloc(128 * 4);
  float* al2  = (float*)alloc(96 * 4);
  float* be2  = (float*)alloc(96 * 4);
  float* alr  = (float*)alloc(96 * 4);
  float* ber  = (float*)alloc(96 * 4);
  float* hsum = (float*)alloc((size_t)Bz * Hh * 4);
  (void)ws_size; (void)in_sizes; (void)n_in; (void)out_size;

  k_prep<<<dim3(224), dim3(256), 0, stream>>>(
      w1, cb1, g1, b1, m1, v1, w2, cb2, g2, b2, m2, v2,
      wr, cbr, gr, br, mr, vr, wx, sbia, wh,
      w1b, w2b, wrb, wxb, bperm, whb, al1, be1, al2, be2, alr, ber);

  k_conv1<<<dim3(Tt / 128, Bz), dim3(256), 0, stream>>>(x, w1b, al1, be1, out1);

  k_conv2<<<dim3(T2 / 64, Bz), dim3(256), 0, stream>>>(out1, w2b, wrb, al2, be2, alr, ber, seqb);

  k_slstm<<<dim3(Bz), dim3(512), 0, stream>>>(seqb, whb, wxb, bperm, hsum);

  k_head<<<dim3(Bz), dim3(128), 0, stream>>>(hsum, fc1w, fc1b, fc2w, fc2b, (float*)d_out);
}